// Round 6
// baseline (190.983 us; speedup 1.0000x reference)
//
#include <hip/hip_runtime.h>
#include <math.h>

#define BH 32
#define L  2048
#define D  64
#define SK 40
#define NT 40
#define NC 64          // key chunks for split-K attention
#define CK 32          // keys per chunk (NC*CK == L)
#define SPB 33         // padded LDS stride for S
#define SCALE 0.125f

// ---- workspace layout (bytes) ----
#define WS_M      0                  // float[BH*L]            = 256 KB
#define WS_MTOP   262144             // int[BH*NT]             = 5 KB
#define WS_VP     267264             // float[1024*64]         = 256 KB
#define WS_VM     529408             // float[BH*D]            = 8 KB
#define WS_QTOP   537600             // float[BH*NT*D]         = 320 KB
#define WS_OPART  865280             // float[BH*NC*NT*D]      = 20.97 MB
#define WS_MPART  21836800           // float[BH*NC*NT]        = 320 KB
#define WS_LPART  22164480           // float[BH*NC*NT]        = 320 KB

// DPP add: VALU-only cross-lane (no DS pipe). ctrl is a template constant.
// 0xB1 = quad_perm [1,0,3,2] (xor1), 0x4E = quad_perm [2,3,0,1] (xor2),
// 0x12C = row_ror:12 -> dest i <- src (i+4) mod 16 (valid at lane%8==0),
// 0x128 = row_ror:8  -> dest i <- src (i+8) mod 16 (valid at lane%16==0).
template <int CTRL>
__device__ __forceinline__ float dpp_add(float x) {
    int y = __builtin_amdgcn_update_dpp(0, __float_as_int(x), CTRL, 0xF, 0xF, true);
    return x + __int_as_float(y);
}

// =============== Kernel 1: fused sampled-scores + V-mean partials ===============
// 16-lane gather (round 5). Three formulations (8-lane, 16-lane, LDS-stream)
// all land ~42us = 671MB/42us ~ 16TB/s of random 64B-line traffic -- the
// invariant is LINES/instr (16 both ways), so this is the L1 miss-fill
// ceiling for the pattern. This round: only cheap ILP tweaks (unroll 8,
// split mx/sm accumulator chains); a null here CONFIRMS the ceiling.
__global__ __launch_bounds__(512) void kMV(const float* __restrict__ Q,
                                           const float* __restrict__ K,
                                           const float* __restrict__ V,
                                           const int* __restrict__ idx,
                                           float* __restrict__ M,
                                           float* __restrict__ Vp)
{
    __shared__ int   sidx[64 * SK];    // 10 KB
    __shared__ float red[512];

    int t    = threadIdx.x;
    int b    = blockIdx.x;
    int head = ((b >> 3) & 3) * 8 + (b & 7);   // XCD-swizzled head
    int qc   = b >> 5;                         // 0..31
    int l0   = qc * 64;

    // ---- V-mean partial for rows l0..l0+63 of this head ----
    {
        int d = t & 63, r = t >> 6;            // r = 0..7
        const float* Vb = V + ((size_t)head * L + l0 + r * 8) * D + d;
        float acc = 0.f;
        #pragma unroll
        for (int k = 0; k < 8; ++k) acc += Vb[(size_t)k * D];
        red[t] = acc;
    }
    // ---- stage index rows (contiguous) ----
    for (int i = t; i < 64 * SK; i += 512) sidx[i] = idx[l0 * SK + i];
    __syncthreads();
    if (t < 64) {
        float s = 0.f;
        #pragma unroll
        for (int rr = 0; rr < 8; ++rr) s += red[t + rr * 64];
        Vp[(head * 32 + qc) * 64 + t] = s;
    }

    // ---- sampled-scores path: 16-lane groups, 4 queries per wave-round ----
    int wave = t >> 6, lane = t & 63;
    int g16  = lane >> 4;                      // query within wave-round, 0..3
    int dl   = lane & 15;                      // float4 slot of D (full row!)

    const float4* Q4  = reinterpret_cast<const float4*>(Q);
    const float4* Kb4 = reinterpret_cast<const float4*>(K) + (size_t)head * L * 16;

    #pragma unroll
    for (int qr = 0; qr < 2; ++qr) {
        int lq = wave * 8 + qr * 4 + g16;      // 0..63
        size_t qid = (size_t)head * L + (l0 + lq);
        float4 q4 = Q4[qid * 16 + dl];         // coalesced: 4 full Q rows / wave

        float mx0 = -INFINITY, mx1 = -INFINITY, sm0 = 0.f, sm1 = 0.f;
        #pragma unroll 8
        for (int s = 0; s < SK; ++s) {
            int kr = sidx[lq * SK + s];        // group-uniform (broadcast)
            float4 k4 = Kb4[(size_t)kr * 16 + dl];   // 4 rows x 256B contiguous
            float p = q4.x * k4.x + q4.y * k4.y + q4.z * k4.z + q4.w * k4.w;
            p = dpp_add<0xB1>(p);              // + lane^1
            p = dpp_add<0x4E>(p);              // + lane^2
            p = dpp_add<0x12C>(p);             // + lane+4 (valid at dl%8==0)
            p = dpp_add<0x128>(p);             // + lane+8 (valid at dl==0)
            if (s & 1) { mx1 = fmaxf(mx1, p); sm1 += p; }
            else       { mx0 = fmaxf(mx0, p); sm0 += p; }
        }
        if (dl == 0) M[qid] = fmaxf(mx0, mx1) - (sm0 + sm1) * (1.0f / (float)L);
    }
}

// =============== Kernel 2: top-40 (radix select) + V-mean finalize + Q gather ===============
__global__ __launch_bounds__(256) void kTopVm(const float* __restrict__ M,
                                              const float* __restrict__ Vp,
                                              const float* __restrict__ Q,
                                              int* __restrict__ Mtop,
                                              float* __restrict__ Vm,
                                              float* __restrict__ Qtop)
{
    __shared__ unsigned int keys[L];
    __shared__ int hist[256];
    __shared__ int wtot[4];
    __shared__ unsigned int pref_s;
    __shared__ int krem_s;
    __shared__ int cnt_gt, cnt_eq;
    __shared__ int eqlist[64];
    __shared__ int stop[NT];

    int bh = blockIdx.x;
    int t  = threadIdx.x;
    int lane = t & 63, w = t >> 6;

    if (t < 64) {
        float s = 0.f;
        #pragma unroll
        for (int c = 0; c < 32; ++c) s += Vp[(bh * 32 + c) * 64 + t];
        Vm[bh * D + t] = s * (1.0f / (float)L);
    }

    for (int i = t; i < L; i += 256) {
        unsigned int u = __float_as_uint(M[bh * L + i]);
        keys[i] = (u & 0x80000000u) ? ~u : (u | 0x80000000u);
    }
    if (t == 0) { pref_s = 0u; krem_s = NT; cnt_gt = 0; cnt_eq = 0; }
    __syncthreads();

    #pragma unroll
    for (int shift = 24; shift >= 0; shift -= 8) {
        hist[t] = 0;
        __syncthreads();                               // BAR_A (orders prev pref/krem writes)
        unsigned int pref = pref_s;
        int krem = krem_s;
        for (int i = t; i < L; i += 256) {
            unsigned int k  = keys[i];
            unsigned int hi = (shift == 24) ? 0u : (k >> (shift + 8));
            if (hi == pref) atomicAdd(&hist[(k >> shift) & 0xFF], 1);
        }
        __syncthreads();                               // BAR_B
        int h = hist[t];
        int v = h;                                     // inclusive suffix-scan in-wave
        #pragma unroll
        for (int o = 1; o < 64; o <<= 1) {
            int u = __shfl_down(v, o, 64);
            if (lane + o < 64) v += u;
        }
        if (lane == 0) wtot[w] = v;                    // wave totals
        __syncthreads();                               // BAR_C
        int ss = v;                                    // ssum[t] = sum_{j>=t} hist[j]
        #pragma unroll
        for (int w2 = 1; w2 < 4; ++w2) if (w2 > w) ss += wtot[w2];
        if (ss - h < krem && ss >= krem) {             // exactly one thread matches
            krem_s = krem - (ss - h);
            pref_s = (pref << 8) | (unsigned int)t;
        }
    }
    __syncthreads();                                   // publish final pref_s/krem_s

    unsigned int T = pref_s;
    int krem = krem_s;
    for (int i = t; i < L; i += 256) {
        unsigned int k = keys[i];
        if (k > T) {
            int p = atomicAdd(&cnt_gt, 1);
            Mtop[bh * NT + p] = i;
            stop[p] = i;
        } else if (k == T) {
            int p = atomicAdd(&cnt_eq, 1);
            if (p < 64) eqlist[p] = i;
        }
    }
    __syncthreads();
    if (t == 0) {
        int base = cnt_gt;
        int m = cnt_eq < 64 ? cnt_eq : 64;
        for (int q = 0; q < krem; ++q) {
            int best = 0x7fffffff, bj = -1;
            for (int j = 0; j < m; ++j) if (eqlist[j] < best) { best = eqlist[j]; bj = j; }
            Mtop[bh * NT + base + q] = best;
            stop[base + q] = best;
            if (bj >= 0) eqlist[bj] = 0x7fffffff;
        }
    }
    __syncthreads();
    // gather selected Q rows into compact Qtop (read wave-uniform in kAttnPart)
    const float4* Qg = reinterpret_cast<const float4*>(Q) + (size_t)bh * L * 16;
    float4* Qt = reinterpret_cast<float4*>(Qtop) + (size_t)bh * NT * 16;
    for (int i = t; i < NT * 16; i += 256)
        Qt[i] = Qg[(size_t)stop[i >> 4] * 16 + (i & 15)];
}

// =============== Kernel 3: split-K attention partials + V_mean broadcast fill ===============
// OCCUPANCY REWRITE: CK 64->32, NC 32->64 (2048 blocks). Two lanes share a
// key row, each owning half of D (k[8] = 32 VGPR; dot combined with one
// shfl_xor(32)). LDS 27.1 -> 13.6 KB, grid 4 -> 8 blocks/CU-capable ->
// 24-32 waves/CU (was 16). V staged in a tight region AFTER phase A
// (round-4 lesson: no cross-phase staging regs -> no spill, lower peak VGPR).
__global__ __launch_bounds__(256) void kAttnPart(const float* __restrict__ Qtop,
                                                 const float* __restrict__ K,
                                                 const float* __restrict__ V,
                                                 const float* __restrict__ Vm,
                                                 float* __restrict__ Opart,
                                                 float* __restrict__ mpart,
                                                 float* __restrict__ lpart,
                                                 float* __restrict__ out)
{
    __shared__ float4 V4s[CK * 16];        // 8 KB, swizzled
    __shared__ float  S[NT * SPB];         // 5.2 KB, exp(scores)
    __shared__ float  smax[NT], ssum[NT];

    int c = blockIdx.x, bh = blockIdx.y;
    int t = threadIdx.x;

    // ---- broadcast fill of this block's 32-row output slice with V_mean ----
    {
        const float4* Vm4 = reinterpret_cast<const float4*>(Vm + bh * D);
        float4* outB = reinterpret_cast<float4*>(out) + ((size_t)bh * L + c * CK) * 16;
        #pragma unroll
        for (int k = 0; k < 2; ++k) { int i = t + k * 256; outB[i] = Vm4[i & 15]; }
    }

    // ---- K half-rows into registers: lane owns row (lane&31), half (lane>>5) ----
    int w    = __builtin_amdgcn_readfirstlane(t) >> 6;   // scalar wave id
    int lane = t & 63;
    int row  = lane & 31;
    int dh   = (lane >> 5) * 8;                          // half offset, float4 units
    const float4* Kg = reinterpret_cast<const float4*>(K) + ((size_t)bh * L + c * CK) * 16;
    float4 k[8];
    #pragma unroll
    for (int d4 = 0; d4 < 8; ++d4) k[d4] = Kg[row * 16 + dh + d4];

    // ---- Phase A: wave w scores its 10 queries against the 32 keys ----
    const float4* Qb = reinterpret_cast<const float4*>(Qtop) + ((size_t)bh * NT + w * 10) * 16;
    float p[10];
    #pragma unroll
    for (int i = 0; i < 10; ++i) {
        float a0 = 0.f;
        #pragma unroll
        for (int d4 = 0; d4 < 8; ++d4) {
            float4 q4 = Qb[i * 16 + dh + d4];          // 2 distinct addrs/wave, L1
            a0 += q4.x * k[d4].x + q4.y * k[d4].y + q4.z * k[d4].z + q4.w * k[d4].w;
        }
        a0 += __shfl_xor(a0, 32, 64);                  // combine D-halves
        p[i] = a0 * SCALE;
    }

    // ---- in-register softmax per u (partial over this chunk); exp(S) -> LDS ----
    #pragma unroll
    for (int i = 0; i < 10; ++i) {
        int u = w * 10 + i;
        float m = p[i];
        #pragma unroll
        for (int o = 1; o < 32; o <<= 1) m = fmaxf(m, __shfl_xor(m, o, 64));
        float e = __expf(p[i] - m);
        float l2 = e;
        #pragma unroll
        for (int o = 1; o < 32; o <<= 1) l2 += __shfl_xor(l2, o, 64);
        if (lane < 32) S[u * SPB + row] = e;
        if (lane == 0) { smax[u] = m; ssum[u] = l2; }
    }

    // ---- V -> LDS (tight stage: load, wait, swizzled write) ----
    {
        const float4* Vg = reinterpret_cast<const float4*>(V) + ((size_t)bh * L + c * CK) * 16;
        float4 v0 = Vg[t];
        float4 v1 = Vg[t + 256];
        int i0 = t,       j0 = i0 >> 4, c0 = i0 & 15;
        int i1 = t + 256, j1 = i1 >> 4, c1 = i1 & 15;
        V4s[j0 * 16 + (c0 ^ (j0 & 15))] = v0;
        V4s[j1 * 16 + (c1 ^ (j1 & 15))] = v1;
    }
    __syncthreads();

    // ---- Phase B: O[u][d] = sum_j P[u][j] V[j][d], register-tiled ----
    {
        int a = t >> 5, r = t & 31;
        int d4 = r >> 1, jh = r & 1;
        float4 acc[5];
        #pragma unroll
        for (int ui = 0; ui < 5; ++ui) acc[ui] = make_float4(0.f, 0.f, 0.f, 0.f);
        for (int jj = 0; jj < 16; ++jj) {
            int j = jh * 16 + jj;
            float4 v4 = V4s[j * 16 + (d4 ^ (j & 15))];
            #pragma unroll
            for (int ui = 0; ui < 5; ++ui) {
                float pw = S[(a + 8 * ui) * SPB + j];
                acc[ui].x += pw * v4.x; acc[ui].y += pw * v4.y;
                acc[ui].z += pw * v4.z; acc[ui].w += pw * v4.w;
            }
        }
        #pragma unroll
        for (int ui = 0; ui < 5; ++ui) {       // combine jh pairs via quad_perm xor1
            acc[ui].x = dpp_add<0xB1>(acc[ui].x);
            acc[ui].y = dpp_add<0xB1>(acc[ui].y);
            acc[ui].z = dpp_add<0xB1>(acc[ui].z);
            acc[ui].w = dpp_add<0xB1>(acc[ui].w);
        }
        if (jh == 0) {
            float4* Og = reinterpret_cast<float4*>(Opart) + ((size_t)(bh * NC + c) * NT) * 16;
            #pragma unroll
            for (int ui = 0; ui < 5; ++ui)
                Og[(a + 8 * ui) * 16 + d4] = acc[ui];
        }
    }
    if (t < NT) {
        mpart[(bh * NC + c) * NT + t] = smax[t];
        lpart[(bh * NC + c) * NT + t] = ssum[t];
    }
}

// =============== Kernel 4: combine partials, overwrite selected rows ===============
// De-chained: global max first, then den/o as sums of INDEPENDENT weighted terms.
__global__ __launch_bounds__(64) void kCombine(const float* __restrict__ Opart,
                                               const float* __restrict__ mpart,
                                               const float* __restrict__ lpart,
                                               const int* __restrict__ Mtop,
                                               float* __restrict__ out)
{
    int u = blockIdx.x, bh = blockIdx.y, d = threadIdx.x;
    float gm = -INFINITY;
    #pragma unroll 8
    for (int c = 0; c < NC; ++c) gm = fmaxf(gm, mpart[(bh * NC + c) * NT + u]);
    float den = 0.f, o = 0.f;
    #pragma unroll 8
    for (int c = 0; c < NC; ++c) {
        int pi = (bh * NC + c) * NT + u;
        float wgt = __expf(mpart[pi] - gm);
        den += wgt * lpart[pi];
        o   += wgt * Opart[(size_t)pi * D + d];
    }
    int qrow = Mtop[bh * NT + u];
    out[((size_t)bh * L + qrow) * D + d] = o / den;
}

extern "C" void kernel_launch(void* const* d_in, const int* in_sizes, int n_in,
                              void* d_out, int out_size, void* d_ws, size_t ws_size,
                              hipStream_t stream)
{
    const float* Q   = (const float*)d_in[0];
    const float* K   = (const float*)d_in[1];
    const float* V   = (const float*)d_in[2];
    const int*   idx = (const int*)d_in[3];
    float* out = (float*)d_out;

    char* ws = (char*)d_ws;
    float* M     = (float*)(ws + WS_M);
    int*   Mtop  = (int*)  (ws + WS_MTOP);
    float* Vp    = (float*)(ws + WS_VP);
    float* Vm    = (float*)(ws + WS_VM);
    float* Qtop  = (float*)(ws + WS_QTOP);
    float* Opart = (float*)(ws + WS_OPART);
    float* mpart = (float*)(ws + WS_MPART);
    float* lpart = (float*)(ws + WS_LPART);

    kMV      <<<1024, 512, 0, stream>>>(Q, K, V, idx, M, Vp);
    kTopVm   <<<BH, 256, 0, stream>>>(M, Vp, Q, Mtop, Vm, Qtop);
    kAttnPart<<<dim3(NC, BH), 256, 0, stream>>>(Qtop, K, V, Vm, Opart, mpart, lpart, out);
    kCombine <<<dim3(NT, BH), 64, 0, stream>>>(Opart, mpart, lpart, Mtop, out);
}

// Round 7
// 161.351 us; speedup vs baseline: 1.1837x; 1.1837x over previous
//
#include <hip/hip_runtime.h>
#include <math.h>

#define BH 32
#define L  2048
#define D  64
#define SK 40
#define NT 40
#define NC 32          // key chunks for split-K attention
#define CK 64          // keys per chunk (NC*CK == L)
#define SP 65          // padded LDS stride for S (2-way max = free)
#define SCALE 0.125f

// ---- workspace layout (bytes) ----
#define WS_M      0                  // float[BH*L]            = 256 KB
#define WS_MTOP   262144             // int[BH*NT]             = 5 KB
#define WS_VP     267264             // float[1024*64]         = 256 KB
#define WS_VM     529408             // float[BH*D]            = 8 KB
#define WS_QTOP   537600             // float[BH*NT*D]         = 320 KB
#define WS_OPART  865280             // float[BH*NC*NT*D]      = 10.49 MB
#define WS_MPART  11351040           // float[BH*NC*NT]        = 160 KB
#define WS_LPART  11514880           // float[BH*NC*NT]        = 160 KB

// DPP add: VALU-only cross-lane (no DS pipe). ctrl is a template constant.
// 0xB1 = quad_perm [1,0,3,2] (xor1), 0x4E = quad_perm [2,3,0,1] (xor2),
// 0x12C = row_ror:12 -> dest i <- src (i+4) mod 16 (valid at lane%8==0),
// 0x128 = row_ror:8  -> dest i <- src (i+8) mod 16 (valid at lane%16==0).
template <int CTRL>
__device__ __forceinline__ float dpp_add(float x) {
    int y = __builtin_amdgcn_update_dpp(0, __float_as_int(x), CTRL, 0xF, 0xF, true);
    return x + __int_as_float(y);
}

// =============== Kernel 1: fused sampled-scores + V-mean partials ===============
// 16-lane gather. Three formulations (8-lane, 16-lane, LDS-stream) all land
// ~42us = 671MB of random 64B-line traffic at ~16TB/s -- the L1 miss-fill
// ceiling for this pattern (ILP tweaks null). Held at this form.
__global__ __launch_bounds__(512) void kMV(const float* __restrict__ Q,
                                           const float* __restrict__ K,
                                           const float* __restrict__ V,
                                           const int* __restrict__ idx,
                                           float* __restrict__ M,
                                           float* __restrict__ Vp)
{
    __shared__ int   sidx[64 * SK];    // 10 KB
    __shared__ float red[512];

    int t    = threadIdx.x;
    int b    = blockIdx.x;
    int head = ((b >> 3) & 3) * 8 + (b & 7);   // XCD-swizzled head
    int qc   = b >> 5;                         // 0..31
    int l0   = qc * 64;

    // ---- V-mean partial for rows l0..l0+63 of this head ----
    {
        int d = t & 63, r = t >> 6;            // r = 0..7
        const float* Vb = V + ((size_t)head * L + l0 + r * 8) * D + d;
        float acc = 0.f;
        #pragma unroll
        for (int k = 0; k < 8; ++k) acc += Vb[(size_t)k * D];
        red[t] = acc;
    }
    // ---- stage index rows (contiguous) ----
    for (int i = t; i < 64 * SK; i += 512) sidx[i] = idx[l0 * SK + i];
    __syncthreads();
    if (t < 64) {
        float s = 0.f;
        #pragma unroll
        for (int rr = 0; rr < 8; ++rr) s += red[t + rr * 64];
        Vp[(head * 32 + qc) * 64 + t] = s;
    }

    // ---- sampled-scores path: 16-lane groups, 4 queries per wave-round ----
    int wave = t >> 6, lane = t & 63;
    int g16  = lane >> 4;                      // query within wave-round, 0..3
    int dl   = lane & 15;                      // float4 slot of D (full row!)

    const float4* Q4  = reinterpret_cast<const float4*>(Q);
    const float4* Kb4 = reinterpret_cast<const float4*>(K) + (size_t)head * L * 16;

    #pragma unroll
    for (int qr = 0; qr < 2; ++qr) {
        int lq = wave * 8 + qr * 4 + g16;      // 0..63
        size_t qid = (size_t)head * L + (l0 + lq);
        float4 q4 = Q4[qid * 16 + dl];         // coalesced: 4 full Q rows / wave

        float mx0 = -INFINITY, mx1 = -INFINITY, sm0 = 0.f, sm1 = 0.f;
        #pragma unroll 8
        for (int s = 0; s < SK; ++s) {
            int kr = sidx[lq * SK + s];        // group-uniform (broadcast)
            float4 k4 = Kb4[(size_t)kr * 16 + dl];   // 4 rows x 256B contiguous
            float p = q4.x * k4.x + q4.y * k4.y + q4.z * k4.z + q4.w * k4.w;
            p = dpp_add<0xB1>(p);              // + lane^1
            p = dpp_add<0x4E>(p);              // + lane^2
            p = dpp_add<0x12C>(p);             // + lane+4 (valid at dl%8==0)
            p = dpp_add<0x128>(p);             // + lane+8 (valid at dl==0)
            if (s & 1) { mx1 = fmaxf(mx1, p); sm1 += p; }
            else       { mx0 = fmaxf(mx0, p); sm0 += p; }
        }
        if (dl == 0) M[qid] = fmaxf(mx0, mx1) - (sm0 + sm1) * (1.0f / (float)L);
    }
}

// =============== Kernel 2: top-40 (radix select) + V-mean finalize + Q gather ===============
// 1024 threads (was 256): key-stage / histogram / classify loops drop 8 -> 2
// iterations; barrier count unchanged. Radix bookkeeping confined to t<256
// with uniform barrier structure.
__global__ __launch_bounds__(1024) void kTopVm(const float* __restrict__ M,
                                               const float* __restrict__ Vp,
                                               const float* __restrict__ Q,
                                               int* __restrict__ Mtop,
                                               float* __restrict__ Vm,
                                               float* __restrict__ Qtop)
{
    __shared__ unsigned int keys[L];
    __shared__ int hist[256];
    __shared__ int wtot[4];
    __shared__ unsigned int pref_s;
    __shared__ int krem_s;
    __shared__ int cnt_gt, cnt_eq;
    __shared__ int eqlist[64];
    __shared__ int stop[NT];

    int bh = blockIdx.x;
    int t  = threadIdx.x;
    int lane = t & 63, w = t >> 6;

    if (t < 64) {
        float s = 0.f;
        #pragma unroll
        for (int c = 0; c < 32; ++c) s += Vp[(bh * 32 + c) * 64 + t];
        Vm[bh * D + t] = s * (1.0f / (float)L);
    }

    for (int i = t; i < L; i += 1024) {
        unsigned int u = __float_as_uint(M[bh * L + i]);
        keys[i] = (u & 0x80000000u) ? ~u : (u | 0x80000000u);
    }
    if (t == 0) { pref_s = 0u; krem_s = NT; cnt_gt = 0; cnt_eq = 0; }
    __syncthreads();

    #pragma unroll
    for (int shift = 24; shift >= 0; shift -= 8) {
        if (t < 256) hist[t] = 0;
        __syncthreads();                               // BAR_A (orders prev pref/krem writes)
        unsigned int pref = pref_s;
        int krem = krem_s;
        for (int i = t; i < L; i += 1024) {
            unsigned int k  = keys[i];
            unsigned int hi = (shift == 24) ? 0u : (k >> (shift + 8));
            if (hi == pref) atomicAdd(&hist[(k >> shift) & 0xFF], 1);
        }
        __syncthreads();                               // BAR_B
        int h = 0, v = 0;
        if (t < 256) {
            h = hist[t];
            v = h;                                     // inclusive suffix-scan in-wave
            #pragma unroll
            for (int o = 1; o < 64; o <<= 1) {
                int u = __shfl_down(v, o, 64);
                if (lane + o < 64) v += u;
            }
            if (lane == 0) wtot[w] = v;                // wave totals (waves 0..3)
        }
        __syncthreads();                               // BAR_C
        if (t < 256) {
            int ss = v;                                // ssum[t] = sum_{j>=t} hist[j]
            #pragma unroll
            for (int w2 = 1; w2 < 4; ++w2) if (w2 > w) ss += wtot[w2];
            if (ss - h < krem && ss >= krem) {         // exactly one thread matches
                krem_s = krem - (ss - h);
                pref_s = (pref << 8) | (unsigned int)t;
            }
        }
    }
    __syncthreads();                                   // publish final pref_s/krem_s

    unsigned int T = pref_s;
    int krem = krem_s;
    for (int i = t; i < L; i += 1024) {
        unsigned int k = keys[i];
        if (k > T) {
            int p = atomicAdd(&cnt_gt, 1);
            Mtop[bh * NT + p] = i;
            stop[p] = i;
        } else if (k == T) {
            int p = atomicAdd(&cnt_eq, 1);
            if (p < 64) eqlist[p] = i;
        }
    }
    __syncthreads();
    if (t == 0) {
        int base = cnt_gt;
        int m = cnt_eq < 64 ? cnt_eq : 64;
        for (int q = 0; q < krem; ++q) {
            int best = 0x7fffffff, bj = -1;
            for (int j = 0; j < m; ++j) if (eqlist[j] < best) { best = eqlist[j]; bj = j; }
            Mtop[bh * NT + base + q] = best;
            stop[base + q] = best;
            if (bj >= 0) eqlist[bj] = 0x7fffffff;
        }
    }
    __syncthreads();
    // gather selected Q rows into compact Qtop (read wave-uniform in kAttnPart)
    const float4* Qg = reinterpret_cast<const float4*>(Q) + (size_t)bh * L * 16;
    float4* Qt = reinterpret_cast<float4*>(Qtop) + (size_t)bh * NT * 16;
    for (int i = t; i < NT * 16; i += 1024)
        Qt[i] = Qg[(size_t)stop[i >> 4] * 16 + (i & 15)];
}

// =============== Kernel 3: split-K attention partials + V_mean broadcast fill ===============
// ROUND-2 GEOMETRY (CK=64, NC=32) -- the CK=32 split (round 6) doubled split-K
// overhead (Opart 2x, softmax 2x) without the predicted occupancy gain and
// regressed to 53us. Lane owns ONE key row -> k[16] = 64 VGPRs in registers.
__global__ __launch_bounds__(256) void kAttnPart(const float* __restrict__ Qtop,
                                                 const float* __restrict__ K,
                                                 const float* __restrict__ V,
                                                 const float* __restrict__ Vm,
                                                 float* __restrict__ Opart,
                                                 float* __restrict__ mpart,
                                                 float* __restrict__ lpart,
                                                 float* __restrict__ out)
{
    __shared__ float4 V4s[CK * 16];        // 16 KB, swizzled
    __shared__ float  S[NT * SP];          // 10.4 KB, exp(scores)
    __shared__ float  smax[NT], ssum[NT];

    int c = blockIdx.x, bh = blockIdx.y;
    int t = threadIdx.x;

    // ---- broadcast fill of this block's 64-row output slice with V_mean ----
    {
        const float4* Vm4 = reinterpret_cast<const float4*>(Vm + bh * D);
        float4* outB = reinterpret_cast<float4*>(out) + ((size_t)bh * L + c * CK) * 16;
        #pragma unroll
        for (int k = 0; k < 4; ++k) { int i = t + k * 256; outB[i] = Vm4[i & 15]; }
    }

    // ---- V chunk loads (coalesced, into regs; LDS write after phase A) ----
    const float4* Vg = reinterpret_cast<const float4*>(V) + ((size_t)bh * L + c * CK) * 16;
    float4 vreg[4];
    #pragma unroll
    for (int k = 0; k < 4; ++k) vreg[k] = Vg[t + k * 256];

    // ---- K rows into registers: lane owns row j = lane (all waves same rows, L1) ----
    int w    = __builtin_amdgcn_readfirstlane(t) >> 6;   // scalar wave id
    int lane = t & 63;
    const float4* Kg = reinterpret_cast<const float4*>(K) + ((size_t)bh * L + c * CK) * 16;
    float4 k[16];
    #pragma unroll
    for (int d4 = 0; d4 < 16; ++d4) k[d4] = Kg[(size_t)lane * 16 + d4];

    // ---- Phase A: wave w scores its 10 queries against the 64 keys ----
    const float4* Qb = reinterpret_cast<const float4*>(Qtop) + ((size_t)bh * NT + w * 10) * 16;
    float p[10];
    #pragma unroll
    for (int i = 0; i < 10; ++i) {
        float a0 = 0.f;
        #pragma unroll
        for (int d4 = 0; d4 < 16; ++d4) {
            float4 q4 = Qb[i * 16 + d4];               // wave-uniform, L1-resident
            a0 += q4.x * k[d4].x + q4.y * k[d4].y + q4.z * k[d4].z + q4.w * k[d4].w;
        }
        p[i] = a0 * SCALE;
    }

    // ---- in-register softmax per u (partial over this chunk); exp(S) -> LDS ----
    #pragma unroll
    for (int i = 0; i < 10; ++i) {
        int u = w * 10 + i;
        float m = p[i];
        #pragma unroll
        for (int o = 1; o < 64; o <<= 1) m = fmaxf(m, __shfl_xor(m, o, 64));
        float e = __expf(p[i] - m);
        float l2 = e;
        #pragma unroll
        for (int o = 1; o < 64; o <<= 1) l2 += __shfl_xor(l2, o, 64);
        S[u * SP + lane] = e;
        if (lane == 0) { smax[u] = m; ssum[u] = l2; }
    }

    // ---- V -> LDS (swizzled) ----
    #pragma unroll
    for (int kk = 0; kk < 4; ++kk) {
        int i = t + kk * 256;
        int j = i >> 4, d4 = i & 15;
        V4s[j * 16 + (d4 ^ (j & 15))] = vreg[kk];
    }
    __syncthreads();

    // ---- Phase B: O[u][d] = sum_j P[u][j] V[j][d], register-tiled ----
    {
        int a = t >> 5, r = t & 31;
        int d4 = r >> 1, jh = r & 1;
        float4 acc[5];
        #pragma unroll
        for (int ui = 0; ui < 5; ++ui) acc[ui] = make_float4(0.f, 0.f, 0.f, 0.f);
        for (int jj = 0; jj < 32; ++jj) {
            int j = jh * 32 + jj;
            float4 v4 = V4s[j * 16 + (d4 ^ (j & 15))];
            #pragma unroll
            for (int ui = 0; ui < 5; ++ui) {
                float pw = S[(a + 8 * ui) * SP + j];
                acc[ui].x += pw * v4.x; acc[ui].y += pw * v4.y;
                acc[ui].z += pw * v4.z; acc[ui].w += pw * v4.w;
            }
        }
        #pragma unroll
        for (int ui = 0; ui < 5; ++ui) {       // combine jh pairs via quad_perm xor1
            acc[ui].x = dpp_add<0xB1>(acc[ui].x);
            acc[ui].y = dpp_add<0xB1>(acc[ui].y);
            acc[ui].z = dpp_add<0xB1>(acc[ui].z);
            acc[ui].w = dpp_add<0xB1>(acc[ui].w);
        }
        if (jh == 0) {
            float4* Og = reinterpret_cast<float4*>(Opart) + ((size_t)(bh * NC + c) * NT) * 16;
            #pragma unroll
            for (int ui = 0; ui < 5; ++ui)
                Og[(a + 8 * ui) * 16 + d4] = acc[ui];
        }
    }
    if (t < NT) {
        mpart[(bh * NC + c) * NT + t] = smax[t];
        lpart[(bh * NC + c) * NT + t] = ssum[t];
    }
}

// =============== Kernel 4: combine partials, overwrite selected rows ===============
// 256 threads / 4 queries per block (grid 1280 -> 320 blocks): amortizes
// launch + gives each block 4 waves. De-chained independent weighted sums.
__global__ __launch_bounds__(256) void kCombine(const float* __restrict__ Opart,
                                                const float* __restrict__ mpart,
                                                const float* __restrict__ lpart,
                                                const int* __restrict__ Mtop,
                                                float* __restrict__ out)
{
    int t = threadIdx.x, bh = blockIdx.y;
    int u = blockIdx.x * 4 + (t >> 6);
    int d = t & 63;
    float gm = -INFINITY;
    #pragma unroll
    for (int c = 0; c < NC; ++c) gm = fmaxf(gm, mpart[(bh * NC + c) * NT + u]);
    float den = 0.f, o = 0.f;
    #pragma unroll
    for (int c = 0; c < NC; ++c) {
        int pi = (bh * NC + c) * NT + u;
        float wgt = __expf(mpart[pi] - gm);
        den += wgt * lpart[pi];
        o   += wgt * Opart[(size_t)pi * D + d];
    }
    int qrow = Mtop[bh * NT + u];
    out[((size_t)bh * L + qrow) * D + d] = o / den;
}

extern "C" void kernel_launch(void* const* d_in, const int* in_sizes, int n_in,
                              void* d_out, int out_size, void* d_ws, size_t ws_size,
                              hipStream_t stream)
{
    const float* Q   = (const float*)d_in[0];
    const float* K   = (const float*)d_in[1];
    const float* V   = (const float*)d_in[2];
    const int*   idx = (const int*)d_in[3];
    float* out = (float*)d_out;

    char* ws = (char*)d_ws;
    float* M     = (float*)(ws + WS_M);
    int*   Mtop  = (int*)  (ws + WS_MTOP);
    float* Vp    = (float*)(ws + WS_VP);
    float* Vm    = (float*)(ws + WS_VM);
    float* Qtop  = (float*)(ws + WS_QTOP);
    float* Opart = (float*)(ws + WS_OPART);
    float* mpart = (float*)(ws + WS_MPART);
    float* lpart = (float*)(ws + WS_LPART);

    kMV      <<<1024, 512, 0, stream>>>(Q, K, V, idx, M, Vp);
    kTopVm   <<<BH, 1024, 0, stream>>>(M, Vp, Q, Mtop, Vm, Qtop);
    kAttnPart<<<dim3(NC, BH), 256, 0, stream>>>(Qtop, K, V, Vm, Opart, mpart, lpart, out);
    kCombine <<<dim3(NT / 4, BH), 256, 0, stream>>>(Opart, mpart, lpart, Mtop, out);
}